// Round 1
// baseline (242.942 us; speedup 1.0000x reference)
//
#include <hip/hip_runtime.h>
#include <math.h>

#define NTOK 16384
#define DIM 2048
#define NEXP 64
#define TB 32              // tokens per block (2 MFMA token-tiles)
#define NSTAGE 64          // K chunks of 32

// flat output offsets (return order)
#define OFF_W    0
#define OFF_I    32768
#define OFF_P    65536
#define OFF_ENT  1114112
#define OFF_CONF 1114113
#define OFF_UTIL 1114114

typedef short s16x8 __attribute__((ext_vector_type(8)));
typedef float f32x4 __attribute__((ext_vector_type(4)));

__device__ __forceinline__ unsigned short f2bf(float v) {
    unsigned u = __builtin_bit_cast(unsigned, v);
    u = u + 0x7FFFu + ((u >> 16) & 1u);          // RNE
    return (unsigned short)(u >> 16);
}
__device__ __forceinline__ float bf2f(unsigned short b) {
    return __builtin_bit_cast(float, (unsigned)b << 16);
}

__global__ void router_init(float* __restrict__ out) {
    int tid = threadIdx.x;
    if (tid < 66) out[OFF_ENT + tid] = 0.0f;
}

// Split W into 3 bf16 planes (hi/mid/lo), fragment-linear (verified r4/r5):
// plane p, chunk c, ntile nt, lane l -> uint4 at wsp[p*16384 + c*256 + nt*64 + l]
// fragment element j: W[16nt + (l&15)][32c + 8*(l>>4) + j]
__global__ void router_wsplit(const float* __restrict__ Wg, uint4* __restrict__ wsp) {
    const int c = blockIdx.x;
    const int t = threadIdx.x;
    const int nt = t >> 6, l = t & 63;
    const int e  = 16 * nt + (l & 15);
    const int k0 = 32 * c + 8 * (l >> 4);
    const float* src = Wg + (size_t)e * DIM + k0;
    float4 a = *(const float4*)src;
    float4 b = *(const float4*)(src + 4);
    float v[8] = {a.x, a.y, a.z, a.w, b.x, b.y, b.z, b.w};
    unsigned short H[8], M[8], L[8];
    #pragma unroll
    for (int j = 0; j < 8; ++j) {
        H[j] = f2bf(v[j]);  float r = v[j] - bf2f(H[j]);
        M[j] = f2bf(r);     r = r - bf2f(M[j]);
        L[j] = f2bf(r);
    }
    uint4 ph, pm, pl;
    ph.x = H[0] | ((unsigned)H[1] << 16); ph.y = H[2] | ((unsigned)H[3] << 16);
    ph.z = H[4] | ((unsigned)H[5] << 16); ph.w = H[6] | ((unsigned)H[7] << 16);
    pm.x = M[0] | ((unsigned)M[1] << 16); pm.y = M[2] | ((unsigned)M[3] << 16);
    pm.z = M[4] | ((unsigned)M[5] << 16); pm.w = M[6] | ((unsigned)M[7] << 16);
    pl.x = L[0] | ((unsigned)L[1] << 16); pl.y = L[2] | ((unsigned)L[3] << 16);
    pl.z = L[4] | ((unsigned)L[5] << 16); pl.w = L[6] | ((unsigned)L[7] << 16);
    const int idx = c * 256 + t;
    wsp[idx]         = ph;
    wsp[16384 + idx] = pm;
    wsp[32768 + idx] = pl;
}

// W regs: 2 ntiles (2np, 2np+1) x 3 planes {hi,mid,lo}
#define LOADW(W_, c_) { const int b_ = (c_)*256 + np*128 + l;  \
    W_[0] = wq[b_];          W_[1] = wq[b_ + 64];              \
    W_[2] = wq[16384 + b_];  W_[3] = wq[16384 + b_ + 64];      \
    W_[4] = wq[32768 + b_];  W_[5] = wq[32768 + b_ + 64]; }

// exact truncation split of 8 fp32 -> 3 bf16 planes, packed as uint4 each.
// Identical math to the previous in-loop CONVA -> bit-identical logits.
#define SPLIT8(a0_, a1_, ph_, pm_, pl_) {                                \
    float xv[8] = {a0_.x, a0_.y, a0_.z, a0_.w,                           \
                   a1_.x, a1_.y, a1_.z, a1_.w};                          \
    unsigned hw_[8], mw_[8], lw_[8];                                     \
    _Pragma("unroll")                                                    \
    for (int j = 0; j < 8; ++j) {                                        \
        unsigned u_  = __builtin_bit_cast(unsigned, xv[j]);              \
        unsigned hb_ = u_ & 0xFFFF0000u;                                 \
        float    r_  = xv[j] - __builtin_bit_cast(float, hb_);           \
        unsigned mb_ = __builtin_bit_cast(unsigned, r_) & 0xFFFF0000u;   \
        float    r2_ = r_ - __builtin_bit_cast(float, mb_);              \
        unsigned lb_ = __builtin_bit_cast(unsigned, r2_);                \
        hw_[j] = hb_ >> 16; mw_[j] = mb_ >> 16; lw_[j] = lb_ >> 16;      \
    }                                                                    \
    ph_.x = hw_[0] | (hw_[1] << 16); ph_.y = hw_[2] | (hw_[3] << 16);    \
    ph_.z = hw_[4] | (hw_[5] << 16); ph_.w = hw_[6] | (hw_[7] << 16);    \
    pm_.x = mw_[0] | (mw_[1] << 16); pm_.y = mw_[2] | (mw_[3] << 16);    \
    pm_.z = mw_[4] | (mw_[5] << 16); pm_.w = mw_[6] | (mw_[7] << 16);    \
    pl_.x = lw_[0] | (lw_[1] << 16); pl_.y = lw_[2] | (lw_[3] << 16);    \
    pl_.z = lw_[4] | (lw_[5] << 16); pl_.w = lw_[6] | (lw_[7] << 16);    \
}

// Stage this thread's 8 floats (chunk cc of the pair) into buffer buf_:
// split once here, store 3 bf16 planes. LDS slot sq holds global K-pair sq^(st&3).
#define STAGEW(buf_) {                                                   \
    uint4 ph_, pm_, pl_;                                                 \
    SPLIT8(xr0, xr1, ph_, pm_, pl_);                                     \
    Xp[buf_][0][cc][st][sq] = ph_;                                       \
    Xp[buf_][1][cc][st][sq] = pm_;                                       \
    Xp[buf_][2][cc][st][sq] = pl_;                                       \
}

// Read the lane's A fragment: 3x ds_read_b128, zero VALU.
// Reader wants global K-pair qd of token tl -> LDS slot qd^(tl&3).
#define READA(buf_, cc_) {                                               \
    const int sl_ = qd ^ (tl & 3);                                       \
    ah = __builtin_bit_cast(s16x8, Xp[buf_][0][cc_][tl][sl_]);           \
    am = __builtin_bit_cast(s16x8, Xp[buf_][1][cc_][tl][sl_]);           \
    al = __builtin_bit_cast(s16x8, Xp[buf_][2][cc_][tl][sl_]);           \
}

// 6-product split per tile {hh,mh,hm,mm,hl,lh}; two ntiles interleaved for ILP.
// Order unchanged from verified kernel -> bit-identical accumulation.
#define COMPUTE(W_) {                                                    \
    s16x8 b0h_ = __builtin_bit_cast(s16x8, W_[0]);                       \
    s16x8 b1h_ = __builtin_bit_cast(s16x8, W_[1]);                       \
    s16x8 b0m_ = __builtin_bit_cast(s16x8, W_[2]);                       \
    s16x8 b1m_ = __builtin_bit_cast(s16x8, W_[3]);                       \
    s16x8 b0l_ = __builtin_bit_cast(s16x8, W_[4]);                       \
    s16x8 b1l_ = __builtin_bit_cast(s16x8, W_[5]);                       \
    acc0 = __builtin_amdgcn_mfma_f32_16x16x32_bf16(ah, b0h_, acc0, 0, 0, 0); \
    acc1 = __builtin_amdgcn_mfma_f32_16x16x32_bf16(ah, b1h_, acc1, 0, 0, 0); \
    acc0 = __builtin_amdgcn_mfma_f32_16x16x32_bf16(am, b0h_, acc0, 0, 0, 0); \
    acc1 = __builtin_amdgcn_mfma_f32_16x16x32_bf16(am, b1h_, acc1, 0, 0, 0); \
    acc0 = __builtin_amdgcn_mfma_f32_16x16x32_bf16(ah, b0m_, acc0, 0, 0, 0); \
    acc1 = __builtin_amdgcn_mfma_f32_16x16x32_bf16(ah, b1m_, acc1, 0, 0, 0); \
    acc0 = __builtin_amdgcn_mfma_f32_16x16x32_bf16(am, b0m_, acc0, 0, 0, 0); \
    acc1 = __builtin_amdgcn_mfma_f32_16x16x32_bf16(am, b1m_, acc1, 0, 0, 0); \
    acc0 = __builtin_amdgcn_mfma_f32_16x16x32_bf16(ah, b0l_, acc0, 0, 0, 0); \
    acc1 = __builtin_amdgcn_mfma_f32_16x16x32_bf16(ah, b1l_, acc1, 0, 0, 0); \
    acc0 = __builtin_amdgcn_mfma_f32_16x16x32_bf16(al, b0h_, acc0, 0, 0, 0); \
    acc1 = __builtin_amdgcn_mfma_f32_16x16x32_bf16(al, b1h_, acc1, 0, 0, 0); \
    }

__global__ __launch_bounds__(256, 2) void router_main(
    const float* __restrict__ x, const uint4* __restrict__ wq,
    float* __restrict__ out)
{
    // x staged as 3 bf16 planes: [buf][plane][chunk-of-2][token][4 slots x 16B]. 24 KB
    __shared__ __align__(16) uint4 Xp[2][3][2][TB][4];
    __shared__ float lg[TB][NEXP + 1];
    __shared__ float m1s[TB], rss[TB];
    __shared__ float s_ent, s_conf, s_cnt[NEXP];

    const int tid = threadIdx.x;
    const int l   = tid & 63;
    const int w   = tid >> 6;
    const int np  = __builtin_amdgcn_readfirstlane(w >> 1); // expert-pair (SGPR)
    const int tt  = w & 1;                                  // token-tile
    const int qd  = l >> 4;                                 // K-pair 0..3 (8 elems)
    const int tl  = tt * 16 + (l & 15);                     // local token
    const int t0  = blockIdx.x * TB;

    if (tid == 0) { s_ent = 0.0f; s_conf = 0.0f; }
    if (tid < NEXP) s_cnt[tid] = 0.0f;

    // staging decomposition: tid -> chunk-of-pair cc, token st, LDS slot sq
    const int cc  = tid >> 7;          // 0/1: which chunk of the staged pair
    const int rr  = tid & 127;
    const int st  = rr >> 2;           // token 0..31
    const int sq  = rr & 3;            // LDS 16B pair-slot 0..3
    const int gq  = sq ^ (st & 3);     // global K-pair stored in slot sq
    const float* xsrc = x + (size_t)(t0 + st) * DIM + 8 * gq; // + 32*chunk floats

    f32x4 acc0 = (f32x4)(0.0f), acc1 = (f32x4)(0.0f);
    s16x8 ah, am, al;
    uint4 wA[6], wB[6];
    float4 xr0, xr1;

    // prologue: chunk (0|1 per cc) -> split -> Xp[0]; W chunks 0,1; prefetch chunks 2|3
    xr0 = *(const float4*)(xsrc + cc * 32);
    xr1 = *(const float4*)(xsrc + cc * 32 + 4);
    LOADW(wA, 0); LOADW(wB, 1);
    STAGEW(0);
    xr0 = *(const float4*)(xsrc + (2 + cc) * 32);
    xr1 = *(const float4*)(xsrc + (2 + cc) * 32 + 4);
    __syncthreads();

    for (int s = 0; s < NSTAGE; s += 2) {
        const int buf = (s >> 1) & 1;
        // stage chunks s+2,s+3 into the other buffer (data prefetched last body)
        if (s + 2 < NSTAGE) STAGEW(buf ^ 1);
        // prefetch chunks s+4,s+5 (consumed one barrier from now)
        if (s + 4 < NSTAGE) {
            xr0 = *(const float4*)(xsrc + (s + 4 + cc) * 32);
            xr1 = *(const float4*)(xsrc + (s + 4 + cc) * 32 + 4);
        }
        // chunk s
        READA(buf, 0);
        COMPUTE(wA);
        if (s + 2 < NSTAGE) LOADW(wA, s + 2);
        // chunk s+1
        READA(buf, 1);
        COMPUTE(wB);
        if (s + 3 < NSTAGE) LOADW(wB, s + 3);
        // T4-lite barrier: drain LDS only; global prefetches stay in flight
        // (compiler inserts counted vmcnt at their uses next iteration).
        asm volatile("s_waitcnt lgkmcnt(0)" ::: "memory");
        __builtin_amdgcn_sched_barrier(0);
        __builtin_amdgcn_s_barrier();
        __builtin_amdgcn_sched_barrier(0);
    }

    // C/D layout (verified): col = lane&15 (expert), row = qd*4 + r (token)
    #pragma unroll
    for (int r = 0; r < 4; ++r) {
        lg[tt * 16 + 4 * qd + r][np * 32 + (l & 15)]      = acc0[r];
        lg[tt * 16 + 4 * qd + r][np * 32 + 16 + (l & 15)] = acc1[r];
    }
    __syncthreads();

    // 32 threads: top-2 + softmax stats per token
    if (tid < TB) {
        const int t = tid;
        float m1 = -INFINITY, m2 = -INFINITY;
        int i1 = 0, i2 = 0;
        for (int e = 0; e < NEXP; ++e) {
            float lv = lg[t][e];
            if (lv > m1)      { m2 = m1; i2 = i1; m1 = lv; i1 = e; }
            else if (lv > m2) { m2 = lv; i2 = e; }
        }
        float ssum = 0.0f, tsum = 0.0f;
        for (int e = 0; e < NEXP; ++e) {
            float d = lg[t][e] - m1;
            float ex = __expf(d);
            ssum += ex;
            tsum += d * ex;
        }
        float rs = 1.0f / ssum;
        float H  = logf(ssum) - tsum * rs;   // H = ln(s) - (sum d e^d)/s
        float e2 = __expf(m2 - m1);
        float rn = 1.0f / (1.0f + e2);
        float w0 = rn, w1v = e2 * rn;
        m1s[t] = m1; rss[t] = rs;

        *(float2*)&out[OFF_W + 2 * (t0 + t)] = make_float2(w0, w1v);
        *(float2*)&out[OFF_I + 2 * (t0 + t)] = make_float2((float)i1, (float)i2);

        atomicAdd(&s_ent,  H);
        atomicAdd(&s_conf, w0);
        atomicAdd(&s_cnt[i1], 1.0f);
        atomicAdd(&s_cnt[i2], 1.0f);
    }
    __syncthreads();

    // coalesced probs write: 512 float4s / 256 threads
    #pragma unroll
    for (int p = 0; p < 2; ++p) {
        int Q  = tid + 256 * p;
        int t  = Q >> 4;
        int qq = Q & 15;
        float m  = m1s[t];
        float rs = rss[t];
        float4 pr;
        pr.x = __expf(lg[t][4 * qq + 0] - m) * rs;
        pr.y = __expf(lg[t][4 * qq + 1] - m) * rs;
        pr.z = __expf(lg[t][4 * qq + 2] - m) * rs;
        pr.w = __expf(lg[t][4 * qq + 3] - m) * rs;
        *(float4*)&out[OFF_P + (size_t)(t0 + t) * NEXP + 4 * qq] = pr;
    }

    // stats: pre-scaled so the atomic sums are exact / final means
    if (tid == 0) {
        atomicAdd(&out[OFF_ENT],  s_ent  * (1.0f / 16384.0f));
        atomicAdd(&out[OFF_CONF], s_conf * (1.0f / 16384.0f));
    }
    if (tid < NEXP)
        atomicAdd(&out[OFF_UTIL + tid], s_cnt[tid] * (1.0f / 32768.0f));
}

extern "C" void kernel_launch(void* const* d_in, const int* in_sizes, int n_in,
                              void* d_out, int out_size, void* d_ws, size_t ws_size,
                              hipStream_t stream) {
    const float* x  = (const float*)d_in[0];
    const float* Wg = (const float*)d_in[1];
    float* out = (float*)d_out;
    (void)in_sizes; (void)n_in; (void)out_size; (void)ws_size;

    router_init<<<dim3(1), dim3(128), 0, stream>>>(out);
    router_wsplit<<<dim3(NSTAGE), dim3(256), 0, stream>>>(Wg, (uint4*)d_ws);
    router_main<<<dim3(NTOK / TB), dim3(256), 0, stream>>>(x, (const uint4*)d_ws, out);
}

// Round 2
// 231.163 us; speedup vs baseline: 1.0510x; 1.0510x over previous
//
#include <hip/hip_runtime.h>
#include <math.h>

#define NTOK 16384
#define DIM 2048
#define NEXP 64
#define TB 32              // tokens per block
#define NSG 32             // K chunks (of 32 elems) per K-group; 2 groups cover 64

// flat output offsets (return order)
#define OFF_W    0
#define OFF_I    32768
#define OFF_P    65536
#define OFF_ENT  1114112
#define OFF_CONF 1114113
#define OFF_UTIL 1114114

typedef short s16x8 __attribute__((ext_vector_type(8)));
typedef float f32x4 __attribute__((ext_vector_type(4)));

__device__ __forceinline__ unsigned short f2bf(float v) {
    unsigned u = __builtin_bit_cast(unsigned, v);
    u = u + 0x7FFFu + ((u >> 16) & 1u);          // RNE
    return (unsigned short)(u >> 16);
}
__device__ __forceinline__ float bf2f(unsigned short b) {
    return __builtin_bit_cast(float, (unsigned)b << 16);
}

// Split W into 3 bf16 planes (hi/mid/lo), fragment-linear (verified r4/r5):
// plane p, chunk c, ntile nt, lane l -> uint4 at wsp[p*16384 + c*256 + nt*64 + l]
// fragment element j: W[16nt + (l&15)][32c + 8*(l>>4) + j]
// Also zeroes the 66 stat accumulators (folded former router_init).
__global__ void router_wsplit(const float* __restrict__ Wg, uint4* __restrict__ wsp,
                              float* __restrict__ out) {
    const int c = blockIdx.x;
    const int t = threadIdx.x;
    if (c == 0 && t < 66) out[OFF_ENT + t] = 0.0f;
    const int nt = t >> 6, l = t & 63;
    const int e  = 16 * nt + (l & 15);
    const int k0 = 32 * c + 8 * (l >> 4);
    const float* src = Wg + (size_t)e * DIM + k0;
    float4 a = *(const float4*)src;
    float4 b = *(const float4*)(src + 4);
    float v[8] = {a.x, a.y, a.z, a.w, b.x, b.y, b.z, b.w};
    unsigned short H[8], M[8], L[8];
    #pragma unroll
    for (int j = 0; j < 8; ++j) {
        H[j] = f2bf(v[j]);  float r = v[j] - bf2f(H[j]);
        M[j] = f2bf(r);     r = r - bf2f(M[j]);
        L[j] = f2bf(r);
    }
    uint4 ph, pm, pl;
    ph.x = H[0] | ((unsigned)H[1] << 16); ph.y = H[2] | ((unsigned)H[3] << 16);
    ph.z = H[4] | ((unsigned)H[5] << 16); ph.w = H[6] | ((unsigned)H[7] << 16);
    pm.x = M[0] | ((unsigned)M[1] << 16); pm.y = M[2] | ((unsigned)M[3] << 16);
    pm.z = M[4] | ((unsigned)M[5] << 16); pm.w = M[6] | ((unsigned)M[7] << 16);
    pl.x = L[0] | ((unsigned)L[1] << 16); pl.y = L[2] | ((unsigned)L[3] << 16);
    pl.z = L[4] | ((unsigned)L[5] << 16); pl.w = L[6] | ((unsigned)L[7] << 16);
    const int idx = c * 256 + t;
    wsp[idx]         = ph;
    wsp[16384 + idx] = pm;
    wsp[32768 + idx] = pl;
}

// W regs: 2 ntiles (2np, 2np+1) x 3 planes {hi,mid,lo}
#define LOADW(W_, c_) { const int b_ = (c_)*256 + np*128 + l;  \
    W_[0] = wq[b_];          W_[1] = wq[b_ + 64];              \
    W_[2] = wq[16384 + b_];  W_[3] = wq[16384 + b_ + 64];      \
    W_[4] = wq[32768 + b_];  W_[5] = wq[32768 + b_ + 64]; }

// exact truncation split of 8 fp32 -> 3 bf16 planes, packed as uint4 each.
// Identical math to the verified kernels -> bit-identical per-chunk products.
#define SPLIT8(a0_, a1_, ph_, pm_, pl_) {                                \
    float xv[8] = {a0_.x, a0_.y, a0_.z, a0_.w,                           \
                   a1_.x, a1_.y, a1_.z, a1_.w};                          \
    unsigned hw_[8], mw_[8], lw_[8];                                     \
    _Pragma("unroll")                                                    \
    for (int j = 0; j < 8; ++j) {                                        \
        unsigned u_  = __builtin_bit_cast(unsigned, xv[j]);              \
        unsigned hb_ = u_ & 0xFFFF0000u;                                 \
        float    r_  = xv[j] - __builtin_bit_cast(float, hb_);           \
        unsigned mb_ = __builtin_bit_cast(unsigned, r_) & 0xFFFF0000u;   \
        float    r2_ = r_ - __builtin_bit_cast(float, mb_);              \
        unsigned lb_ = __builtin_bit_cast(unsigned, r2_);                \
        hw_[j] = hb_ >> 16; mw_[j] = mb_ >> 16; lw_[j] = lb_ >> 16;      \
    }                                                                    \
    ph_.x = hw_[0] | (hw_[1] << 16); ph_.y = hw_[2] | (hw_[3] << 16);    \
    ph_.z = hw_[4] | (hw_[5] << 16); ph_.w = hw_[6] | (hw_[7] << 16);    \
    pm_.x = mw_[0] | (mw_[1] << 16); pm_.y = mw_[2] | (mw_[3] << 16);    \
    pm_.z = mw_[4] | (mw_[5] << 16); pm_.w = mw_[6] | (mw_[7] << 16);    \
    pl_.x = lw_[0] | (lw_[1] << 16); pl_.y = lw_[2] | (lw_[3] << 16);    \
    pl_.z = lw_[4] | (lw_[5] << 16); pl_.w = lw_[6] | (lw_[7] << 16);    \
}

// Stage this thread's 8 floats into its K-group's buffer; split once here.
// LDS slot sq of token st holds global K-octet sq ^ ((st>>2)&3)  (bank-even swizzle).
#define STAGEW(buf_) {                                                   \
    uint4 ph_, pm_, pl_;                                                 \
    SPLIT8(xr0, xr1, ph_, pm_, pl_);                                     \
    Xp[g][buf_][0][cc][st][sq] = ph_;                                    \
    Xp[g][buf_][1][cc][st][sq] = pm_;                                    \
    Xp[g][buf_][2][cc][st][sq] = pl_;                                    \
}

// Read the lane's A fragment: 3x ds_read_b128, zero VALU.
// Reader wants K-octet qd of token tl -> slot qd ^ ((tl>>2)&3).
#define READA(buf_, cc_) {                                               \
    ah = __builtin_bit_cast(s16x8, Xp[g][buf_][0][cc_][tl][sl]);         \
    am = __builtin_bit_cast(s16x8, Xp[g][buf_][1][cc_][tl][sl]);         \
    al = __builtin_bit_cast(s16x8, Xp[g][buf_][2][cc_][tl][sl]);         \
}

// 6-product split per tile {hh,mh,hm,mm,hl,lh}; two ntiles interleaved for ILP.
#define COMPUTE(W_) {                                                    \
    s16x8 b0h_ = __builtin_bit_cast(s16x8, W_[0]);                       \
    s16x8 b1h_ = __builtin_bit_cast(s16x8, W_[1]);                       \
    s16x8 b0m_ = __builtin_bit_cast(s16x8, W_[2]);                       \
    s16x8 b1m_ = __builtin_bit_cast(s16x8, W_[3]);                       \
    s16x8 b0l_ = __builtin_bit_cast(s16x8, W_[4]);                       \
    s16x8 b1l_ = __builtin_bit_cast(s16x8, W_[5]);                       \
    acc0 = __builtin_amdgcn_mfma_f32_16x16x32_bf16(ah, b0h_, acc0, 0, 0, 0); \
    acc1 = __builtin_amdgcn_mfma_f32_16x16x32_bf16(ah, b1h_, acc1, 0, 0, 0); \
    acc0 = __builtin_amdgcn_mfma_f32_16x16x32_bf16(am, b0h_, acc0, 0, 0, 0); \
    acc1 = __builtin_amdgcn_mfma_f32_16x16x32_bf16(am, b1h_, acc1, 0, 0, 0); \
    acc0 = __builtin_amdgcn_mfma_f32_16x16x32_bf16(ah, b0m_, acc0, 0, 0, 0); \
    acc1 = __builtin_amdgcn_mfma_f32_16x16x32_bf16(ah, b1m_, acc1, 0, 0, 0); \
    acc0 = __builtin_amdgcn_mfma_f32_16x16x32_bf16(am, b0m_, acc0, 0, 0, 0); \
    acc1 = __builtin_amdgcn_mfma_f32_16x16x32_bf16(am, b1m_, acc1, 0, 0, 0); \
    acc0 = __builtin_amdgcn_mfma_f32_16x16x32_bf16(ah, b0l_, acc0, 0, 0, 0); \
    acc1 = __builtin_amdgcn_mfma_f32_16x16x32_bf16(ah, b1l_, acc1, 0, 0, 0); \
    acc0 = __builtin_amdgcn_mfma_f32_16x16x32_bf16(al, b0h_, acc0, 0, 0, 0); \
    acc1 = __builtin_amdgcn_mfma_f32_16x16x32_bf16(al, b1h_, acc1, 0, 0, 0); \
    }

// 512 threads = 8 waves = 2 K-groups x 4 waves. 2 blocks/CU -> 4 waves/SIMD.
__global__ __launch_bounds__(512, 4) void router_main(
    const float* __restrict__ x, const uint4* __restrict__ wq,
    float* __restrict__ out)
{
    // x staged as 3 bf16 planes per K-group:
    // [group][buf][plane][chunk-of-2][token][4 slots x 16B]. 48 KB
    __shared__ __align__(16) uint4 Xp[2][2][3][2][TB][4];
    __shared__ float lg[TB][NEXP + 1];
    __shared__ float m1s[TB], rss[TB];
    __shared__ float s_ent, s_conf, s_cnt[NEXP];

    const int tid = threadIdx.x;
    const int l   = tid & 63;
    const int w   = tid >> 6;                               // 0..7
    const int g   = tid >> 8;                               // K-group 0/1
    const int lw  = w & 3;                                  // wave within group
    const int np  = __builtin_amdgcn_readfirstlane(lw >> 1);// expert-pair (SGPR)
    const int tt  = lw & 1;                                 // token-tile
    const int qd  = l >> 4;                                 // K-octet 0..3
    const int tl  = tt * 16 + (l & 15);                     // local token
    const int sl  = qd ^ ((tl >> 2) & 3);                   // LDS read slot
    const int t0  = blockIdx.x * TB;
    const int cb  = g * NSG;                                // group chunk base

    if (tid == 0) { s_ent = 0.0f; s_conf = 0.0f; }
    if (tid < NEXP) s_cnt[tid] = 0.0f;

    // staging decomposition within group: gtid -> chunk-of-pair cc, token st, slot sq
    const int gtid = tid & 255;
    const int cc  = gtid >> 7;         // 0/1: which chunk of the staged pair
    const int rr  = gtid & 127;
    const int st  = rr >> 2;           // token 0..31
    const int sq  = rr & 3;            // LDS 16B slot 0..3
    const int gq  = sq ^ ((st >> 2) & 3);  // global K-octet stored in slot sq
    const float* xsrc = x + (size_t)(t0 + st) * DIM + 32 * cb + 8 * gq;

    f32x4 acc0 = (f32x4)(0.0f), acc1 = (f32x4)(0.0f);
    s16x8 ah, am, al;
    uint4 wA[6], wB[6];
    float4 xr0, xr1;

    // prologue: local chunk (0|1 per cc) -> split -> Xp[g][0]; W chunks; prefetch 2|3
    xr0 = *(const float4*)(xsrc + cc * 32);
    xr1 = *(const float4*)(xsrc + cc * 32 + 4);
    LOADW(wA, cb + 0); LOADW(wB, cb + 1);
    STAGEW(0);
    xr0 = *(const float4*)(xsrc + (2 + cc) * 32);
    xr1 = *(const float4*)(xsrc + (2 + cc) * 32 + 4);
    __syncthreads();

    for (int s = 0; s < NSG; s += 2) {
        const int buf = (s >> 1) & 1;
        // stage chunks s+2,s+3 into the other buffer (data prefetched last body)
        if (s + 2 < NSG) STAGEW(buf ^ 1);
        // prefetch chunks s+4,s+5 (consumed one barrier from now)
        if (s + 4 < NSG) {
            xr0 = *(const float4*)(xsrc + (s + 4 + cc) * 32);
            xr1 = *(const float4*)(xsrc + (s + 4 + cc) * 32 + 4);
        }
        // chunk s
        READA(buf, 0);
        COMPUTE(wA);
        if (s + 2 < NSG) LOADW(wA, cb + s + 2);
        // chunk s+1
        READA(buf, 1);
        COMPUTE(wB);
        if (s + 3 < NSG) LOADW(wB, cb + s + 3);
        // LDS-only drain barrier; global prefetches stay in flight across it.
        asm volatile("s_waitcnt lgkmcnt(0)" ::: "memory");
        __builtin_amdgcn_sched_barrier(0);
        __builtin_amdgcn_s_barrier();
        __builtin_amdgcn_sched_barrier(0);
    }

    // combine K-group partials in lg.
    // C/D layout (verified): col = lane&15 (expert), row = qd*4 + r (token)
    if (g == 1) {
        #pragma unroll
        for (int r = 0; r < 4; ++r) {
            lg[tt * 16 + 4 * qd + r][np * 32 + (l & 15)]      = acc0[r];
            lg[tt * 16 + 4 * qd + r][np * 32 + 16 + (l & 15)] = acc1[r];
        }
    }
    __syncthreads();
    if (g == 0) {
        #pragma unroll
        for (int r = 0; r < 4; ++r) {
            lg[tt * 16 + 4 * qd + r][np * 32 + (l & 15)]      += acc0[r];
            lg[tt * 16 + 4 * qd + r][np * 32 + 16 + (l & 15)] += acc1[r];
        }
    }
    __syncthreads();

    // 32 threads: top-2 + softmax stats per token
    if (tid < TB) {
        const int t = tid;
        float m1 = -INFINITY, m2 = -INFINITY;
        int i1 = 0, i2 = 0;
        for (int e = 0; e < NEXP; ++e) {
            float lv = lg[t][e];
            if (lv > m1)      { m2 = m1; i2 = i1; m1 = lv; i1 = e; }
            else if (lv > m2) { m2 = lv; i2 = e; }
        }
        float ssum = 0.0f, tsum = 0.0f;
        for (int e = 0; e < NEXP; ++e) {
            float d = lg[t][e] - m1;
            float ex = __expf(d);
            ssum += ex;
            tsum += d * ex;
        }
        float rs = 1.0f / ssum;
        float H  = logf(ssum) - tsum * rs;   // H = ln(s) - (sum d e^d)/s
        float e2 = __expf(m2 - m1);
        float rn = 1.0f / (1.0f + e2);
        float w0 = rn, w1v = e2 * rn;
        m1s[t] = m1; rss[t] = rs;

        *(float2*)&out[OFF_W + 2 * (t0 + t)] = make_float2(w0, w1v);
        *(float2*)&out[OFF_I + 2 * (t0 + t)] = make_float2((float)i1, (float)i2);

        atomicAdd(&s_ent,  H);
        atomicAdd(&s_conf, w0);
        atomicAdd(&s_cnt[i1], 1.0f);
        atomicAdd(&s_cnt[i2], 1.0f);
    }
    __syncthreads();

    // coalesced probs write: 512 float4s / 512 threads
    {
        int t  = tid >> 4;
        int qq = tid & 15;
        float m  = m1s[t];
        float rs = rss[t];
        float4 pr;
        pr.x = __expf(lg[t][4 * qq + 0] - m) * rs;
        pr.y = __expf(lg[t][4 * qq + 1] - m) * rs;
        pr.z = __expf(lg[t][4 * qq + 2] - m) * rs;
        pr.w = __expf(lg[t][4 * qq + 3] - m) * rs;
        *(float4*)&out[OFF_P + (size_t)(t0 + t) * NEXP + 4 * qq] = pr;
    }

    // stats: pre-scaled so the atomic sums are exact / final means
    if (tid == 0) {
        atomicAdd(&out[OFF_ENT],  s_ent  * (1.0f / 16384.0f));
        atomicAdd(&out[OFF_CONF], s_conf * (1.0f / 16384.0f));
    }
    if (tid < NEXP)
        atomicAdd(&out[OFF_UTIL + tid], s_cnt[tid] * (1.0f / 32768.0f));
}

extern "C" void kernel_launch(void* const* d_in, const int* in_sizes, int n_in,
                              void* d_out, int out_size, void* d_ws, size_t ws_size,
                              hipStream_t stream) {
    const float* x  = (const float*)d_in[0];
    const float* Wg = (const float*)d_in[1];
    float* out = (float*)d_out;
    (void)in_sizes; (void)n_in; (void)out_size; (void)ws_size;

    router_wsplit<<<dim3(64), dim3(256), 0, stream>>>(Wg, (uint4*)d_ws, out);
    router_main<<<dim3(NTOK / TB), dim3(512), 0, stream>>>(x, (const uint4*)d_ws, out);
}